// Round 1
// baseline (58.834 us; speedup 1.0000x reference)
//
#include <hip/hip_runtime.h>

// Problem constants (from setup_inputs): B=256 batches, N=512 keypoints.
#define BATCH 256
#define NPTS  512
#define CENTER_X 0.5f

// Kernel 1: one block per batch. Each thread owns one keypoint.
// Reduces, per symmetric class k in {0,1,2}:
//   su = sum(u), su2 = sum(u^2), sy = sum(y), sy2 = sum(y^2), m = count
// with u = x - CENTER_X. Then:
//   sum_{i<j} (x_i+x_j-2cx)^2 = (m-2)*su2 + su^2
//   sum_{i<j} (y_i-y_j)^2     = m*sy2 - sy^2
//   pairs                     = m*(m-1)/2
// Writes per-batch total to ws[b], per-batch pair count to ws[BATCH+b].
__global__ __launch_bounds__(NPTS) void sym_batch_reduce(
    const float* __restrict__ kp,   // [B, N, 2]
    const int* __restrict__ cls,    // [B, N]
    float* __restrict__ ws) {
  const int b = blockIdx.x;
  const int t = threadIdx.x;

  const float2 p = ((const float2*)kp)[b * NPTS + t];
  const int c = cls[b * NPTS + t];
  const float u = p.x - CENTER_X;
  const float y = p.y;

  float v[15];
#pragma unroll
  for (int k = 0; k < 3; ++k) {
    const float sel = (c == k) ? 1.0f : 0.0f;
    v[5 * k + 0] = sel * u;
    v[5 * k + 1] = sel * u * u;
    v[5 * k + 2] = sel * y;
    v[5 * k + 3] = sel * y * y;
    v[5 * k + 4] = sel;
  }

  // wave (64-lane) butterfly reduce all 15 values
#pragma unroll
  for (int off = 32; off >= 1; off >>= 1) {
#pragma unroll
    for (int i = 0; i < 15; ++i) v[i] += __shfl_down(v[i], off, 64);
  }

  __shared__ float lds[NPTS / 64][15];
  const int wave = t >> 6;
  const int lane = t & 63;
  if (lane == 0) {
#pragma unroll
    for (int i = 0; i < 15; ++i) lds[wave][i] = v[i];
  }
  __syncthreads();

  if (t == 0) {
    float total = 0.0f, count = 0.0f;
#pragma unroll
    for (int k = 0; k < 3; ++k) {
      float su = 0.f, su2 = 0.f, sy = 0.f, sy2 = 0.f, m = 0.f;
#pragma unroll
      for (int w = 0; w < NPTS / 64; ++w) {
        su  += lds[w][5 * k + 0];
        su2 += lds[w][5 * k + 1];
        sy  += lds[w][5 * k + 2];
        sy2 += lds[w][5 * k + 3];
        m   += lds[w][5 * k + 4];
      }
      total += (m - 2.0f) * su2 + su * su + m * sy2 - sy * sy;
      count += 0.5f * m * (m - 1.0f);
    }
    ws[b] = total;
    ws[BATCH + b] = count;
  }
}

// Kernel 2: single 256-thread block reduces the per-batch results and
// writes the final mean.
__global__ __launch_bounds__(BATCH) void sym_final_reduce(
    const float* __restrict__ ws, float* __restrict__ out) {
  const int t = threadIdx.x;
  float total = ws[t];
  float count = ws[BATCH + t];

#pragma unroll
  for (int off = 32; off >= 1; off >>= 1) {
    total += __shfl_down(total, off, 64);
    count += __shfl_down(count, off, 64);
  }

  __shared__ float lt[BATCH / 64], lc[BATCH / 64];
  const int wave = t >> 6;
  const int lane = t & 63;
  if (lane == 0) { lt[wave] = total; lc[wave] = count; }
  __syncthreads();

  if (t == 0) {
    float T = 0.f, C = 0.f;
#pragma unroll
    for (int w = 0; w < BATCH / 64; ++w) { T += lt[w]; C += lc[w]; }
    out[0] = T / fmaxf(C, 1.0f);
  }
}

extern "C" void kernel_launch(void* const* d_in, const int* in_sizes, int n_in,
                              void* d_out, int out_size, void* d_ws, size_t ws_size,
                              hipStream_t stream) {
  const float* kp = (const float*)d_in[0];   // [B, N, 2] float32
  const int* cls = (const int*)d_in[1];      // [B, N] int32
  float* out = (float*)d_out;
  float* ws = (float*)d_ws;                  // needs 2*BATCH floats = 2 KiB

  sym_batch_reduce<<<BATCH, NPTS, 0, stream>>>(kp, cls, ws);
  sym_final_reduce<<<1, BATCH, 0, stream>>>(ws, out);
}